// Round 1
// baseline (213.668 us; speedup 1.0000x reference)
//
#include <hip/hip_runtime.h>

#define N_CHROM 23
#define BINS_PER_CHROM 5000
#define BSZ 16
#define SSZ 512
#define EOS_DIM 512
#define BIN_DIM 256
#define D_MODEL 512
#define ROWS (N_CHROM * BSZ * SSZ)   // 188416
#define PRED_SIZE (ROWS * 3)         // 565248

// Workspace layout (floats):
//   [0,768)        M[3][256]
//   [768,2304)     Meos[3][512]
//   [2304,3408)    ebc[C*B][3]   (includes b_fc and W_fc2·b_eos folded in)
#define WS_M    0
#define WS_MEOS 768
#define WS_EBC  2304

// ---------------------------------------------------------------------------
// Kernel 1: M[n][e] = sum_d W_fc[n][d]     * W_bin[d][e]   (e<256)
//           Meos[n][e] = sum_d W_fc[n][512+d] * W_eos[d][e] (e<512)
// Blocks 0..7 -> M (32 e each); blocks 8..23 -> Meos (32 e each).
// 256 threads: e_local = t&31, d-slice = t>>5 (8 slices of 64 d), LDS reduce.
// ---------------------------------------------------------------------------
__global__ __launch_bounds__(256) void precompute_M(
    const float* __restrict__ W_bin, const float* __restrict__ W_eos,
    const float* __restrict__ W_fc, float* __restrict__ M,
    float* __restrict__ Meos)
{
    __shared__ float wfc_s[3][512];
    __shared__ float red[3][8][32];
    const int bid = blockIdx.x;
    const bool isM = (bid < 8);
    const float* src = isM ? W_bin : W_eos;
    const int ld   = isM ? 256 : 512;
    const int wofs = isM ? 0 : 512;
    const int eb   = (isM ? bid : (bid - 8)) * 32;
    float* dst = isM ? M : Meos;

    const int t = threadIdx.x;
    for (int i = t; i < 3 * 512; i += 256) {
        int n = i >> 9, d = i & 511;
        wfc_s[n][d] = W_fc[n * 1024 + wofs + d];
    }
    __syncthreads();

    const int el = t & 31, slice = t >> 5;
    const int e = eb + el;
    float a0 = 0.f, a1 = 0.f, a2 = 0.f;
    const int d0 = slice * 64;
    for (int dd = 0; dd < 64; ++dd) {
        int d = d0 + dd;
        float v = src[d * ld + e];
        a0 += wfc_s[0][d] * v;
        a1 += wfc_s[1][d] * v;
        a2 += wfc_s[2][d] * v;
    }
    red[0][slice][el] = a0;
    red[1][slice][el] = a1;
    red[2][slice][el] = a2;
    __syncthreads();

    if (slice < 3) {  // t < 96: n = slice
        float s = 0.f;
        for (int q = 0; q < 8; ++q) s += red[slice][q][el];
        dst[slice * ld + e] = s;
    }
}

// ---------------------------------------------------------------------------
// Kernel 2: ebc[cb][n] = b_fc[n] + sum_e ( eos_emb[b][c][e]*Meos[n][e]
//                                        + W_fc[n][512+e]*b_eos[e] )
// One block per (c,b); 3 waves, wave n does one dot of length 512.
// ---------------------------------------------------------------------------
__global__ __launch_bounds__(192) void compute_ebc(
    const float* __restrict__ eos_emb, const float* __restrict__ b_eos,
    const float* __restrict__ W_fc, const float* __restrict__ b_fc,
    const float* __restrict__ Meos, float* __restrict__ ebc)
{
    const int cb = blockIdx.x;           // c*16 + b
    const int c = cb / BSZ, b = cb % BSZ;
    const int n = threadIdx.x >> 6, lane = threadIdx.x & 63;
    const float* eos = eos_emb + ((long long)b * N_CHROM + c) * EOS_DIM;
    const float* me = Meos + n * 512;
    const float* wf2 = W_fc + n * 1024 + 512;
    float s = 0.f;
    for (int e = lane; e < 512; e += 64)
        s += eos[e] * me[e] + wf2[e] * b_eos[e];
    for (int m = 32; m; m >>= 1) s += __shfl_xor(s, m);
    if (lane == 0) ebc[cb * 3 + n] = s + b_fc[n];
}

// ---------------------------------------------------------------------------
// Kernel 3 (main): one wave per 8 rows. Lane holds float4 of table row and its
// 12 M coefficients in registers; 3 butterfly reductions/row; lane0 writes.
// Also copies targets (as float) into second output chunk.
// ---------------------------------------------------------------------------
__global__ __launch_bounds__(256) void main_kernel(
    const int* __restrict__ sampled, const int* __restrict__ targets,
    const float* __restrict__ table, const float* __restrict__ M,
    const float* __restrict__ ebc, float* __restrict__ out)
{
    const int wave = threadIdx.x >> 6, lane = threadIdx.x & 63;
    const long long rbase = ((long long)blockIdx.x * 4 + wave) * 8;
    const int cb = (int)(rbase >> 9);    // rows grouped by (c,b); 32 | 512
    const int c = cb / BSZ;

    // M fragments: lane covers e = 4*lane .. 4*lane+3
    const float4 m0 = ((const float4*)M)[lane];
    const float4 m1 = ((const float4*)M)[64 + lane];
    const float4 m2 = ((const float4*)M)[128 + lane];
    const float e0 = ebc[cb * 3 + 0];
    const float e1 = ebc[cb * 3 + 1];
    const float e2 = ebc[cb * 3 + 2];

    const float* tbase = table + (long long)c * BINS_PER_CHROM * BIN_DIM;

    int myidx = 0;
    if (lane < 8) myidx = sampled[rbase + lane];

    // targets passthrough (second output chunk, as float)
    float* outT = out + PRED_SIZE;
    if (lane < 8) outT[rbase + lane] = (float)targets[rbase + lane];

    for (int k = 0; k < 8; ++k) {
        const int bin = __shfl(myidx, k);
        const float4 v = ((const float4*)(tbase + (long long)bin * BIN_DIM))[lane];
        float p0 = v.x * m0.x + v.y * m0.y + v.z * m0.z + v.w * m0.w;
        float p1 = v.x * m1.x + v.y * m1.y + v.z * m1.z + v.w * m1.w;
        float p2 = v.x * m2.x + v.y * m2.y + v.z * m2.z + v.w * m2.w;
        for (int m = 32; m; m >>= 1) {
            p0 += __shfl_xor(p0, m);
            p1 += __shfl_xor(p1, m);
            p2 += __shfl_xor(p2, m);
        }
        if (lane == 0) {
            const long long o = (rbase + k) * 3;
            out[o + 0] = fmaxf(p0 + e0, 0.f);
            out[o + 1] = fmaxf(p1 + e1, 0.f);
            out[o + 2] = fmaxf(p2 + e2, 0.f);
        }
    }
}

extern "C" void kernel_launch(void* const* d_in, const int* in_sizes, int n_in,
                              void* d_out, int out_size, void* d_ws, size_t ws_size,
                              hipStream_t stream) {
    const float* eos_emb = (const float*)d_in[0];
    const int*   sampled = (const int*)d_in[1];
    const int*   targets = (const int*)d_in[2];
    const float* table   = (const float*)d_in[3];
    const float* W_bin   = (const float*)d_in[4];
    const float* W_eos   = (const float*)d_in[5];
    const float* b_eos   = (const float*)d_in[6];
    const float* W_fc    = (const float*)d_in[7];
    const float* b_fc    = (const float*)d_in[8];
    float* out = (float*)d_out;
    float* ws  = (float*)d_ws;

    float* M    = ws + WS_M;
    float* Meos = ws + WS_MEOS;
    float* ebc  = ws + WS_EBC;

    precompute_M<<<24, 256, 0, stream>>>(W_bin, W_eos, W_fc, M, Meos);
    compute_ebc<<<N_CHROM * BSZ, 192, 0, stream>>>(eos_emb, b_eos, W_fc, b_fc,
                                                   Meos, ebc);
    main_kernel<<<ROWS / 32, 256, 0, stream>>>(sampled, targets, table, M, ebc,
                                               out);
}

// Round 3
// 208.804 us; speedup vs baseline: 1.0233x; 1.0233x over previous
//
#include <hip/hip_runtime.h>

#define N_CHROM 23
#define BINS_PER_CHROM 5000
#define BSZ 16
#define SSZ 512
#define EOS_DIM 512
#define BIN_DIM 256
#define D_MODEL 512
#define VOCAB (N_CHROM * BINS_PER_CHROM)   // 115000
#define ROWS (N_CHROM * BSZ * SSZ)         // 188416
#define PRED_SIZE (ROWS * 3)               // 565248

// Workspace layout (floats):
//   [0,768)        M[3][256]
//   [768,2304)     Meos[3][512]
//   [2304,3408)    ebc[C*B][3]   (includes b_fc and W_fc2·b_eos folded in)
//   [3456, 3456+4*VOCAB)  pt[VOCAB] as float4 (x,y,z = projected logits)
#define WS_M    0
#define WS_MEOS 768
#define WS_EBC  2304
#define WS_PT   3456

// ---------------------------------------------------------------------------
// Kernel 1: M[n][e] = sum_d W_fc[n][d]     * W_bin[d][e]   (e<256)
//           Meos[n][e] = sum_d W_fc[n][512+d] * W_eos[d][e] (e<512)
// ---------------------------------------------------------------------------
__global__ __launch_bounds__(256) void precompute_M(
    const float* __restrict__ W_bin, const float* __restrict__ W_eos,
    const float* __restrict__ W_fc, float* __restrict__ M,
    float* __restrict__ Meos)
{
    __shared__ float wfc_s[3][512];
    __shared__ float red[3][8][32];
    const int bid = blockIdx.x;
    const bool isM = (bid < 8);
    const float* src = isM ? W_bin : W_eos;
    const int ld   = isM ? 256 : 512;
    const int wofs = isM ? 0 : 512;
    const int eb   = (isM ? bid : (bid - 8)) * 32;
    float* dst = isM ? M : Meos;

    const int t = threadIdx.x;
    for (int i = t; i < 3 * 512; i += 256) {
        int n = i >> 9, d = i & 511;
        wfc_s[n][d] = W_fc[n * 1024 + wofs + d];
    }
    __syncthreads();

    const int el = t & 31, slice = t >> 5;
    const int e = eb + el;
    float a0 = 0.f, a1 = 0.f, a2 = 0.f;
    const int d0 = slice * 64;
    for (int dd = 0; dd < 64; ++dd) {
        int d = d0 + dd;
        float v = src[d * ld + e];
        a0 += wfc_s[0][d] * v;
        a1 += wfc_s[1][d] * v;
        a2 += wfc_s[2][d] * v;
    }
    red[0][slice][el] = a0;
    red[1][slice][el] = a1;
    red[2][slice][el] = a2;
    __syncthreads();

    if (slice < 3) {
        float s = 0.f;
        for (int q = 0; q < 8; ++q) s += red[slice][q][el];
        dst[slice * ld + e] = s;
    }
}

// ---------------------------------------------------------------------------
// Kernel 2: ebc[cb][n] = b_fc[n] + sum_e ( eos_emb[b][c][e]*Meos[n][e]
//                                        + W_fc[n][512+e]*b_eos[e] )
// ---------------------------------------------------------------------------
__global__ __launch_bounds__(192) void compute_ebc(
    const float* __restrict__ eos_emb, const float* __restrict__ b_eos,
    const float* __restrict__ W_fc, const float* __restrict__ b_fc,
    const float* __restrict__ Meos, float* __restrict__ ebc)
{
    const int cb = blockIdx.x;           // c*16 + b
    const int c = cb / BSZ, b = cb % BSZ;
    const int n = threadIdx.x >> 6, lane = threadIdx.x & 63;
    const float* eos = eos_emb + ((long long)b * N_CHROM + c) * EOS_DIM;
    const float* me = Meos + n * 512;
    const float* wf2 = W_fc + n * 1024 + 512;
    float s = 0.f;
    for (int e = lane; e < 512; e += 64)
        s += eos[e] * me[e] + wf2[e] * b_eos[e];
    for (int m = 32; m; m >>= 1) s += __shfl_xor(s, m);
    if (lane == 0) ebc[cb * 3 + n] = s + b_fc[n];
}

// ---------------------------------------------------------------------------
// Kernel 3: project the whole embedding table through M once.
// pt[v] = (table[v]·M[0], table[v]·M[1], table[v]·M[2], 0)
// One wave per 8 consecutive rows, streaming, 8 loads in flight.
// VOCAB = 115000 = 8 * 14375, so a wave-uniform rbase check suffices.
// ---------------------------------------------------------------------------
__global__ __launch_bounds__(256) void project_table(
    const float* __restrict__ table, const float* __restrict__ M,
    float4* __restrict__ pt)
{
    const int wave = threadIdx.x >> 6, lane = threadIdx.x & 63;
    const int rbase = (blockIdx.x * 4 + wave) * 8;
    if (rbase >= VOCAB) return;

    const float4 m0 = ((const float4*)M)[lane];
    const float4 m1 = ((const float4*)M)[64 + lane];
    const float4 m2 = ((const float4*)M)[128 + lane];

    const float4* tb = (const float4*)table;
    float4 v[8];
#pragma unroll
    for (int k = 0; k < 8; ++k)
        v[k] = tb[(long long)(rbase + k) * 64 + lane];

#pragma unroll
    for (int k = 0; k < 8; ++k) {
        float p0 = v[k].x * m0.x + v[k].y * m0.y + v[k].z * m0.z + v[k].w * m0.w;
        float p1 = v[k].x * m1.x + v[k].y * m1.y + v[k].z * m1.z + v[k].w * m1.w;
        float p2 = v[k].x * m2.x + v[k].y * m2.y + v[k].z * m2.z + v[k].w * m2.w;
        for (int m = 32; m; m >>= 1) {
            p0 += __shfl_xor(p0, m);
            p1 += __shfl_xor(p1, m);
            p2 += __shfl_xor(p2, m);
        }
        if (lane == 0) pt[rbase + k] = make_float4(p0, p1, p2, 0.f);
    }
}

// ---------------------------------------------------------------------------
// Kernel 4: per-sample 16B gather + bias + relu; targets passthrough.
// ---------------------------------------------------------------------------
__global__ __launch_bounds__(256) void gather_out(
    const int* __restrict__ sampled, const int* __restrict__ targets,
    const float4* __restrict__ pt, const float* __restrict__ ebc,
    float* __restrict__ out)
{
    const int r = blockIdx.x * 256 + threadIdx.x;   // grid sized exactly
    const int c = r >> 13;      // BSZ*SSZ = 8192 rows per chrom
    const int cb = r >> 9;      // 512 rows per (c,b)
    const int bin = sampled[r];
    const float4 p = pt[c * BINS_PER_CHROM + bin];
    const float e0 = ebc[cb * 3 + 0];
    const float e1 = ebc[cb * 3 + 1];
    const float e2 = ebc[cb * 3 + 2];
    const long long o = (long long)r * 3;
    out[o + 0] = fmaxf(p.x + e0, 0.f);
    out[o + 1] = fmaxf(p.y + e1, 0.f);
    out[o + 2] = fmaxf(p.z + e2, 0.f);
    out[PRED_SIZE + r] = (float)targets[r];
}

extern "C" void kernel_launch(void* const* d_in, const int* in_sizes, int n_in,
                              void* d_out, int out_size, void* d_ws, size_t ws_size,
                              hipStream_t stream) {
    const float* eos_emb = (const float*)d_in[0];
    const int*   sampled = (const int*)d_in[1];
    const int*   targets = (const int*)d_in[2];
    const float* table   = (const float*)d_in[3];
    const float* W_bin   = (const float*)d_in[4];
    const float* W_eos   = (const float*)d_in[5];
    const float* b_eos   = (const float*)d_in[6];
    const float* W_fc    = (const float*)d_in[7];
    const float* b_fc    = (const float*)d_in[8];
    float* out = (float*)d_out;
    float* ws  = (float*)d_ws;

    float*  M    = ws + WS_M;
    float*  Meos = ws + WS_MEOS;
    float*  ebc  = ws + WS_EBC;
    float4* pt   = (float4*)(ws + WS_PT);

    precompute_M<<<24, 256, 0, stream>>>(W_bin, W_eos, W_fc, M, Meos);
    compute_ebc<<<N_CHROM * BSZ, 192, 0, stream>>>(eos_emb, b_eos, W_fc, b_fc,
                                                   Meos, ebc);
    // 14375 waves needed; 4 waves/block -> 3594 blocks (last partially idle)
    project_table<<<(VOCAB / 8 + 3) / 4, 256, 0, stream>>>(table, M, pt);
    gather_out<<<ROWS / 256, 256, 0, stream>>>(sampled, targets, pt, ebc, out);
}

// Round 4
// 203.278 us; speedup vs baseline: 1.0511x; 1.0272x over previous
//
#include <hip/hip_runtime.h>

#define N_CHROM 23
#define BINS_PER_CHROM 5000
#define BSZ 16
#define SSZ 512
#define EOS_DIM 512
#define BIN_DIM 256
#define D_MODEL 512
#define VOCAB (N_CHROM * BINS_PER_CHROM)   // 115000
#define ROWS (N_CHROM * BSZ * SSZ)         // 188416
#define PRED_SIZE (ROWS * 3)               // 565248

// Workspace layout (floats):
//   [0,768)        M[3][256]
//   [768,2304)     Meos[3][512]
//   [3456, 3456+4*VOCAB)  pt[VOCAB] as float4 (x,y,z = projected logits)
#define WS_M    0
#define WS_MEOS 768
#define WS_PT   3456

// ---------------------------------------------------------------------------
// Kernel 1: M[n][e] = sum_d W_fc[n][d]     * W_bin[d][e]   (e<256)
//           Meos[n][e] = sum_d W_fc[n][512+d] * W_eos[d][e] (e<512)
// ---------------------------------------------------------------------------
__global__ __launch_bounds__(256) void precompute_M(
    const float* __restrict__ W_bin, const float* __restrict__ W_eos,
    const float* __restrict__ W_fc, float* __restrict__ M,
    float* __restrict__ Meos)
{
    __shared__ float wfc_s[3][512];
    __shared__ float red[3][8][32];
    const int bid = blockIdx.x;
    const bool isM = (bid < 8);
    const float* src = isM ? W_bin : W_eos;
    const int ld   = isM ? 256 : 512;
    const int wofs = isM ? 0 : 512;
    const int eb   = (isM ? bid : (bid - 8)) * 32;
    float* dst = isM ? M : Meos;

    const int t = threadIdx.x;
    for (int i = t; i < 3 * 512; i += 256) {
        int n = i >> 9, d = i & 511;
        wfc_s[n][d] = W_fc[n * 1024 + wofs + d];
    }
    __syncthreads();

    const int el = t & 31, slice = t >> 5;
    const int e = eb + el;
    float a0 = 0.f, a1 = 0.f, a2 = 0.f;
    const int d0 = slice * 64;
    for (int dd = 0; dd < 64; ++dd) {
        int d = d0 + dd;
        float v = src[d * ld + e];
        a0 += wfc_s[0][d] * v;
        a1 += wfc_s[1][d] * v;
        a2 += wfc_s[2][d] * v;
    }
    red[0][slice][el] = a0;
    red[1][slice][el] = a1;
    red[2][slice][el] = a2;
    __syncthreads();

    if (slice < 3) {
        float s = 0.f;
        for (int q = 0; q < 8; ++q) s += red[slice][q][el];
        dst[slice * ld + e] = s;
    }
}

// ---------------------------------------------------------------------------
// Kernel 2: project the whole embedding table through M once.
// pt[v] = (table[v]·M[0], table[v]·M[1], table[v]·M[2], 0)
// One wave per 8 consecutive rows, streaming, 8 loads in flight.
// ---------------------------------------------------------------------------
__global__ __launch_bounds__(256) void project_table(
    const float* __restrict__ table, const float* __restrict__ M,
    float4* __restrict__ pt)
{
    const int wave = threadIdx.x >> 6, lane = threadIdx.x & 63;
    const int rbase = (blockIdx.x * 4 + wave) * 8;
    if (rbase >= VOCAB) return;

    const float4 m0 = ((const float4*)M)[lane];
    const float4 m1 = ((const float4*)M)[64 + lane];
    const float4 m2 = ((const float4*)M)[128 + lane];

    const float4* tb = (const float4*)table;
    float4 v[8];
#pragma unroll
    for (int k = 0; k < 8; ++k)
        v[k] = tb[(long long)(rbase + k) * 64 + lane];

#pragma unroll
    for (int k = 0; k < 8; ++k) {
        float p0 = v[k].x * m0.x + v[k].y * m0.y + v[k].z * m0.z + v[k].w * m0.w;
        float p1 = v[k].x * m1.x + v[k].y * m1.y + v[k].z * m1.z + v[k].w * m1.w;
        float p2 = v[k].x * m2.x + v[k].y * m2.y + v[k].z * m2.z + v[k].w * m2.w;
        for (int m = 32; m; m >>= 1) {
            p0 += __shfl_xor(p0, m);
            p1 += __shfl_xor(p1, m);
            p2 += __shfl_xor(p2, m);
        }
        if (lane == 0) pt[rbase + k] = make_float4(p0, p1, p2, 0.f);
    }
}

// ---------------------------------------------------------------------------
// Kernel 3: fused ebc + gather + relu + targets passthrough.
// Each block covers 256 consecutive rows r = bid*256.. -> all one (c,b) since
// 512 rows per cb and blocks are 256-aligned. Waves 0..2 compute the 3 ebc
// scalars (dot of 512 over Meos/eos + folded b_eos, b_fc terms) into LDS,
// then every thread does the 16B pt gather and writes 3 relu'd floats.
// ---------------------------------------------------------------------------
__global__ __launch_bounds__(256) void gather_out(
    const int* __restrict__ sampled, const int* __restrict__ targets,
    const float4* __restrict__ pt, const float* __restrict__ Meos,
    const float* __restrict__ eos_emb, const float* __restrict__ b_eos,
    const float* __restrict__ W_fc, const float* __restrict__ b_fc,
    float* __restrict__ out)
{
    __shared__ float ebc_s[3];
    const int r = blockIdx.x * 256 + threadIdx.x;
    const int cb = blockIdx.x >> 1;          // 512 rows per (c,b)
    const int c = cb / BSZ, b = cb % BSZ;

    // issue the independent loads first
    const int bin = sampled[r];
    const int tgt = targets[r];

    const int w = threadIdx.x >> 6, lane = threadIdx.x & 63;
    if (w < 3) {
        const float* eos = eos_emb + ((long long)b * N_CHROM + c) * EOS_DIM;
        const float* me  = Meos + w * 512;
        const float* wf2 = W_fc + w * 1024 + 512;
        float s = 0.f;
#pragma unroll
        for (int e0 = 0; e0 < 512; e0 += 64) {
            int e = e0 + lane;
            s += eos[e] * me[e] + wf2[e] * b_eos[e];
        }
        for (int m = 32; m; m >>= 1) s += __shfl_xor(s, m);
        if (lane == 0) ebc_s[w] = s + b_fc[w];
    }
    __syncthreads();

    const float4 p = pt[c * BINS_PER_CHROM + bin];
    const long long o = (long long)r * 3;
    out[o + 0] = fmaxf(p.x + ebc_s[0], 0.f);
    out[o + 1] = fmaxf(p.y + ebc_s[1], 0.f);
    out[o + 2] = fmaxf(p.z + ebc_s[2], 0.f);
    out[PRED_SIZE + r] = (float)tgt;
}

extern "C" void kernel_launch(void* const* d_in, const int* in_sizes, int n_in,
                              void* d_out, int out_size, void* d_ws, size_t ws_size,
                              hipStream_t stream) {
    const float* eos_emb = (const float*)d_in[0];
    const int*   sampled = (const int*)d_in[1];
    const int*   targets = (const int*)d_in[2];
    const float* table   = (const float*)d_in[3];
    const float* W_bin   = (const float*)d_in[4];
    const float* W_eos   = (const float*)d_in[5];
    const float* b_eos   = (const float*)d_in[6];
    const float* W_fc    = (const float*)d_in[7];
    const float* b_fc    = (const float*)d_in[8];
    float* out = (float*)d_out;
    float* ws  = (float*)d_ws;

    float*  M    = ws + WS_M;
    float*  Meos = ws + WS_MEOS;
    float4* pt   = (float4*)(ws + WS_PT);

    precompute_M<<<24, 256, 0, stream>>>(W_bin, W_eos, W_fc, M, Meos);
    // 14375 waves needed; 4 waves/block -> 3594 blocks (last partially idle)
    project_table<<<(VOCAB / 8 + 3) / 4, 256, 0, stream>>>(table, M, pt);
    gather_out<<<ROWS / 256, 256, 0, stream>>>(sampled, targets, pt, Meos,
                                               eos_emb, b_eos, W_fc, b_fc, out);
}